// Round 12
// baseline (6233.575 us; speedup 1.0000x reference)
//
#include <hip/hip_runtime.h>
#include <math.h>

// B=256, T=256, D=80, H=512, 4H=2048, K=512
#define BB 256
#define TT 256
#define DDIM 80
#define HDIM 512
#define ROWSTRIDE 20480   // T*D

// ws layout (float offsets)
#define WS_HA    0          // 131072 (zeroed: enc h0 / final z)
#define WS_CD    131072     // 131072 (zeroed: dec cell state)
#define WS_BAR   262144     // int flags: enc [0..127], dec [256..383]
#define WS_HB    263168
#define WS_QUANT 394240
#define WS_VQP   525312
#define WS_BENC  525568
#define WS_BDEC0 527616
#define WS_BEFF  529664
#define WS_WEFF  531712     // 2048*512

typedef _Float16 f16;
typedef f16 half4_t __attribute__((ext_vector_type(4)));
typedef f16 half8_t __attribute__((ext_vector_type(8)));
typedef float float4_t __attribute__((ext_vector_type(4)));

// fast gate activations (v_exp_f32 + v_rcp_f32); saturation-safe, |err|~1e-7
__device__ __forceinline__ float sigmoid_fast(float v) {
  return __builtin_amdgcn_rcpf(1.0f + __builtin_amdgcn_exp2f(-1.44269504f * v));
}
__device__ __forceinline__ float tanh_fast(float v) {
  return 2.0f * __builtin_amdgcn_rcpf(1.0f + __builtin_amdgcn_exp2f(-2.88539008f * v)) - 1.0f;
}

// LLC-coherent (bypass L1/L2) primitives
__device__ __forceinline__ void llc_store_f32(float* p, float v) {
  asm volatile("global_store_dword %0, %1, off sc0 sc1" :: "v"(p), "v"(v) : "memory");
}
__device__ __forceinline__ void llc_store_i32(int* p, int v) {
  asm volatile("global_store_dword %0, %1, off sc0 sc1" :: "v"(p), "v"(v) : "memory");
}
__device__ __forceinline__ void wait_vm0() {
  asm volatile("s_waitcnt vmcnt(0)" ::: "memory");
}

// 4-deep pipelined flag poll (sampling period ~RT/4); wave-uniform exit via
// vcc; vmcnt(0) drain on exit keeps later counted waits correct.
__device__ __forceinline__ void poll_flag4(const int* fp, int done) {
  int a0, a1, a2, a3;
  asm volatile(
      "global_load_dword %0, %4, off sc0 sc1\n\t"
      "global_load_dword %1, %4, off sc0 sc1\n\t"
      "global_load_dword %2, %4, off sc0 sc1\n\t"
      "Lpoll%=:\n\t"
      "global_load_dword %3, %4, off sc0 sc1\n\t"
      "s_waitcnt vmcnt(3)\n\t"
      "v_cmp_gt_i32 vcc, %5, %0\n\t"
      "s_cbranch_vccz Ldone%=\n\t"
      "global_load_dword %0, %4, off sc0 sc1\n\t"
      "s_waitcnt vmcnt(3)\n\t"
      "v_cmp_gt_i32 vcc, %5, %1\n\t"
      "s_cbranch_vccz Ldone%=\n\t"
      "global_load_dword %1, %4, off sc0 sc1\n\t"
      "s_waitcnt vmcnt(3)\n\t"
      "v_cmp_gt_i32 vcc, %5, %2\n\t"
      "s_cbranch_vccz Ldone%=\n\t"
      "global_load_dword %2, %4, off sc0 sc1\n\t"
      "s_waitcnt vmcnt(3)\n\t"
      "v_cmp_gt_i32 vcc, %5, %3\n\t"
      "s_cbranch_vccnz Lpoll%=\n\t"
      "Ldone%=:\n\t"
      "s_waitcnt vmcnt(0)"
      : "=&v"(a0), "=&v"(a1), "=&v"(a2), "=&v"(a3)
      : "v"(fp), "s"(done)
      : "vcc", "memory");
}

__global__ __launch_bounds__(256) void zero_kernel(float4* __restrict__ p, int n4) {
  int i = blockIdx.x * 256 + threadIdx.x;
  if (i < n4) p[i] = make_float4(0.f, 0.f, 0.f, 0.f);
}

__global__ __launch_bounds__(256) void bias_init_kernel(
    const float* __restrict__ eb1, const float* __restrict__ eb2,
    const float* __restrict__ db1, const float* __restrict__ db2,
    const float* __restrict__ dWih, const float* __restrict__ fcb,
    float* __restrict__ b_enc, float* __restrict__ b_dec0,
    float* __restrict__ b_eff) {
  int n = blockIdx.x * 256 + threadIdx.x;
  b_enc[n] = eb1[n] + eb2[n];
  float bd = db1[n] + db2[n];
  b_dec0[n] = bd;
  float acc = bd;
  #pragma unroll 16
  for (int d = 0; d < DDIM; d++) acc += dWih[n * DDIM + d] * fcb[d];
  b_eff[n] = acc;
}

// W_eff = dec_W_hh + dec_W_ih @ fc_W  (2048x512, K=80)
__global__ __launch_bounds__(256) void fold_kernel(
    const float* __restrict__ dWih, const float* __restrict__ dWhh,
    const float* __restrict__ fcW, float* __restrict__ W_eff) {
  int n = blockIdx.x;
  int tid = threadIdx.x;
  __shared__ float sw[DDIM];
  if (tid < DDIM) sw[tid] = dWih[n * DDIM + tid];
  __syncthreads();
  for (int k = tid; k < HDIM; k += 256) {
    float acc = dWhh[n * HDIM + k];
    #pragma unroll 16
    for (int d = 0; d < DDIM; d++) acc += sw[d] * fcW[d * HDIM + k];
    W_eff[n * HDIM + k] = acc;
  }
}

// ---------------- single LSTM step (decoder t=0 only; x = 0) ---------------------
__global__ __launch_bounds__(256) void lstm_step_kernel(
    const float* __restrict__ Whh, const float* __restrict__ bias,
    const float* __restrict__ h_in, float* __restrict__ c,
    float* __restrict__ h_out) {
  __shared__ float sh[16][516];
  int tid = threadIdx.x;
  int rt = blockIdx.x & 15, jt = blockIdx.x >> 4;
  int row0 = rt << 4;
  for (int i = tid; i < 2048; i += 256) {
    int r = i >> 7, kq = i & 127;
    float4 v = *(const float4*)(h_in + (size_t)(row0 + r) * HDIM + (kq << 2));
    *(float4*)&sh[r][kq << 2] = v;
  }
  __syncthreads();
  int r = tid & 15, j0 = tid >> 4;
  int j = (jt << 4) + j0;
  float a0 = bias[j], a1 = bias[512 + j], a2 = bias[1024 + j], a3 = bias[1536 + j];
  const float4* w0 = (const float4*)(Whh + (size_t)j * HDIM);
  const float4* w1 = (const float4*)(Whh + (size_t)(512 + j) * HDIM);
  const float4* w2 = (const float4*)(Whh + (size_t)(1024 + j) * HDIM);
  const float4* w3 = (const float4*)(Whh + (size_t)(1536 + j) * HDIM);
  const float4* hv = (const float4*)&sh[r][0];
  #pragma unroll 4
  for (int kq = 0; kq < 128; kq++) {
    float4 h4 = hv[kq];
    float4 q0 = w0[kq], q1 = w1[kq], q2 = w2[kq], q3 = w3[kq];
    a0 += h4.x * q0.x + h4.y * q0.y + h4.z * q0.z + h4.w * q0.w;
    a1 += h4.x * q1.x + h4.y * q1.y + h4.z * q1.z + h4.w * q1.w;
    a2 += h4.x * q2.x + h4.y * q2.y + h4.z * q2.z + h4.w * q2.w;
    a3 += h4.x * q3.x + h4.y * q3.y + h4.z * q3.z + h4.w * q3.w;
  }
  size_t idx = (size_t)(row0 + r) * HDIM + j;
  float cv = c[idx];
  float cn = sigmoid_fast(a1) * cv + sigmoid_fast(a0) * tanh_fast(a2);
  float hn = sigmoid_fast(a3) * tanh_fast(cn);
  c[idx] = cn;
  h_out[idx] = hn;
}

// ---------------- persistent MFMA LSTM (split-fp16, register-stationary W) -------
// R12: 128 blocks x 1024 threads (16 waves). Block (rt=bid&15, jt=bid>>4, jt
// in 0..7): rows [rt*16,+16), h-dims [jt*64,+64) -> 256 gate rows. HALVES the
// coherent read redundancy (8 readers/row-group instead of 16: 4.2 MB/step)
// and the barrier group (8 producers). Waves: nt=wv&3 (gate), dq=wv>>2 (dim
// 16-tile). Per-wave MFMA count and W footprint identical to the verified R11.
// Staging: 2x dwordx4/thread, split-K pipeline (vmcnt(1)/vmcnt(0) + rule #18
// fences). Fast activations; flag FIRST; dec y (16 waves x 1 kt) after flag;
// 4-deep pipelined poll over 8 flags.
template <int IS_DEC>
__global__ __launch_bounds__(1024, 4) void lstm_persist(
    const float* __restrict__ W,      // enc: eWhh; dec: W_eff  [2048][512]
    const float* __restrict__ Wih,    // enc only [2048][80]
    const float* __restrict__ bias,   // [2048]
    const float* __restrict__ traj,   // enc only
    const float* __restrict__ c_init, // dec: cD (holds c_1)
    const float* __restrict__ fcW, const float* __restrict__ fcb,
    float* __restrict__ recon,
    float* __restrict__ hA, float* __restrict__ hB,
    int* __restrict__ flags) {
  constexpr int KT  = IS_DEC ? 16 : 19;    // k-tiles of 32 (enc: 512 h + 80 x + pad)
  constexpr int AST = IS_DEC ? 520 : 616;  // f16 row stride (16B aligned)
  constexpr int RST = 260;                 // red row stride (floats; 256 cols)
  __shared__ f16 Ahi[16 * AST];
  __shared__ f16 Alo[16 * AST];
  __shared__ float red[16 * RST];          // gates: 16 rows x 256 cols
  __shared__ float ypart[IS_DEC ? 16 * 260 : 4];

  const int tid = threadIdx.x;
  const int bid = blockIdx.x;
  const int rt = bid & 15, jt = bid >> 4;  // jt in 0..7
  const int r0 = rt * 16, d0 = jt * 64;
  const int wv = __builtin_amdgcn_readfirstlane(tid >> 6);  // 0..15
  const int l15 = tid & 15;
  const int q = (tid >> 4) & 3;            // quad within wave
  const int nt = wv & 3, dq = wv >> 2;     // gate type, dim 16-tile

  // stage one float4 (column-split map: thread -> row=tid>>6, col-quad
  // (tid&63)+k*64) into split-fp16 LDS
  #define SPLITC(vv, k) { \
    int off = (tid >> 6) * AST + (((tid & 63) + (k) * 64) << 2); \
    half4_t hi4, lo4; \
    float f0 = vv.x, f1 = vv.y, f2 = vv.z, f3 = vv.w; \
    f16 a = (f16)f0, b = (f16)f1, cc = (f16)f2, d = (f16)f3; \
    hi4[0] = a; hi4[1] = b; hi4[2] = cc; hi4[3] = d; \
    lo4[0] = (f16)(f0 - (float)a); lo4[1] = (f16)(f1 - (float)b); \
    lo4[2] = (f16)(f2 - (float)cc); lo4[3] = (f16)(f3 - (float)d); \
    *(half4_t*)&Ahi[off] = hi4; *(half4_t*)&Alo[off] = lo4; }

  // ---- register-stationary W: split-fp16 B-fragments ----
  const int grow = nt * 512 + d0 + dq * 16 + l15;  // global gate row
  half8_t Whi[KT], Wlo[KT];
  #pragma unroll
  for (int kt = 0; kt < KT; kt++) {
    #pragma unroll
    for (int j = 0; j < 8; j++) {
      int k = kt * 32 + q * 8 + j;
      float w;
      if (k < 512) w = W[(size_t)grow * HDIM + k];
      else {
        int kx = k - 512;
        w = (!IS_DEC && kx < DDIM) ? Wih[(size_t)grow * DDIM + kx] : 0.f;
      }
      f16 hi = (f16)w;
      Whi[kt][j] = hi;
      Wlo[kt][j] = (f16)(w - (float)hi);
    }
  }
  const float breg = bias[grow];

  // dec: fcW fragments for fused y (jt<5 -> recon dims [jt*16,+16);
  // k-split: wave wv handles k-tile wv)
  half8_t Fhi, Flo;
  float ybias = 0.f;
  if (IS_DEC && jt < 5) {
    const int drow = jt * 16 + l15;
    #pragma unroll
    for (int j = 0; j < 8; j++) {
      float w = fcW[(size_t)drow * HDIM + wv * 32 + q * 8 + j];
      f16 hi = (f16)w;
      Fhi[j] = hi;
      Flo[j] = (f16)(w - (float)hi);
    }
    ybias = fcb[jt * 16 + l15];
  }

  const int eb = tid >> 6, ed = tid & 63;  // elementwise (row, dim)
  float c_reg = IS_DEC ? c_init[(size_t)(r0 + eb) * HDIM + d0 + ed] : 0.f;
  __syncthreads();

  #define MFMA_RANGE(LO, HI) { \
    _Pragma("unroll") \
    for (int kt = (LO); kt < (HI); kt++) { \
      half8_t ahi = *(const half8_t*)&Ahi[abase + kt * 32]; \
      half8_t alo = *(const half8_t*)&Alo[abase + kt * 32]; \
      if (kt & 1) { \
        acc1 = __builtin_amdgcn_mfma_f32_16x16x32_f16(ahi, Whi[kt], acc1, 0, 0, 0); \
        acc1 = __builtin_amdgcn_mfma_f32_16x16x32_f16(alo, Whi[kt], acc1, 0, 0, 0); \
        acc1 = __builtin_amdgcn_mfma_f32_16x16x32_f16(ahi, Wlo[kt], acc1, 0, 0, 0); \
        acc1 = __builtin_amdgcn_mfma_f32_16x16x32_f16(alo, Wlo[kt], acc1, 0, 0, 0); \
      } else { \
        acc0 = __builtin_amdgcn_mfma_f32_16x16x32_f16(ahi, Whi[kt], acc0, 0, 0, 0); \
        acc0 = __builtin_amdgcn_mfma_f32_16x16x32_f16(alo, Whi[kt], acc0, 0, 0, 0); \
        acc0 = __builtin_amdgcn_mfma_f32_16x16x32_f16(ahi, Wlo[kt], acc0, 0, 0, 0); \
        acc0 = __builtin_amdgcn_mfma_f32_16x16x32_f16(alo, Wlo[kt], acc0, 0, 0, 0); \
      } \
    } }

  const int t_begin = IS_DEC ? 1 : 0;
  for (int t = t_begin; t < TT; t++) {
    const float* hin = (t & 1) ? hB : hA;
    float* hout = (t & 1) ? hA : hB;

    // ---- enc: x prefetch FIRST (plain cached; counted by vmcnt below) ----
    float4 xv0;
    if (!IS_DEC && tid < 384) {   // 16 rows x 24 quads (cols 512..608, pad>592)
      int row = tid / 24, c4 = tid % 24;
      xv0 = (c4 < 20)
          ? *(const float4*)(traj + (size_t)(r0 + row) * ROWSTRIDE +
                             (size_t)t * DDIM + c4 * 4)
          : make_float4(0.f, 0.f, 0.f, 0.f);
    }

    // ---- phase 1: issue both h loads; vmcnt(1) fence; stage cols 0..255 ----
    float4 v0, v1;
    const float4* base =
        (const float4*)(hin + (size_t)r0 * HDIM) + (tid >> 6) * 128 + (tid & 63);
    const bool is_t0 = (!IS_DEC && t == 0);
    if (!is_t0) {
      asm volatile(
          "global_load_dwordx4 %0, %2, off sc0 sc1\n\t"
          "global_load_dwordx4 %1, %3, off sc0 sc1"
          : "=&v"(v0), "=&v"(v1)
          : "v"(base), "v"(base + 64)
          : "memory");
      asm volatile("s_waitcnt vmcnt(1)" ::: "memory");
      __builtin_amdgcn_sched_barrier(0);   // rule #18: no hoisting above the wait
      SPLITC(v0, 0);
    } else {
      // enc t=0: h0 = 0 (fill this thread's two col-quads; x staged in phase 2)
      const int fo = (tid >> 6) * AST + ((tid & 63) << 2);
      half4_t z4 = {(f16)0, (f16)0, (f16)0, (f16)0};
      *(half4_t*)&Ahi[fo] = z4; *(half4_t*)&Ahi[fo + 256] = z4;
      *(half4_t*)&Alo[fo] = z4; *(half4_t*)&Alo[fo + 256] = z4;
    }
    __syncthreads();

    // ---- MFMA kt 0..7 (cols 0..255) overlaps drain of cols 256..511 ----
    float4_t acc0 = {breg, breg, breg, breg};
    float4_t acc1 = {0.f, 0.f, 0.f, 0.f};
    const int abase = l15 * AST + q * 8;
    MFMA_RANGE(0, 8);

    // ---- phase 2: drain rest; stage cols 256..511 (+x); MFMA kt 8..KT ----
    if (!is_t0) {
      asm volatile("s_waitcnt vmcnt(0)" ::: "memory");
      __builtin_amdgcn_sched_barrier(0);   // fence: SPLITC stays below the wait
      SPLITC(v1, 1);
    }
    if (!IS_DEC && tid < 384) {  // x tile -> LDS
      int row = tid / 24, c4 = tid % 24;
      int off = row * AST + 512 + c4 * 4;
      half4_t hi4, lo4;
      float f0 = xv0.x, f1 = xv0.y, f2 = xv0.z, f3 = xv0.w;
      f16 a = (f16)f0, b = (f16)f1, cc = (f16)f2, d = (f16)f3;
      hi4[0] = a; hi4[1] = b; hi4[2] = cc; hi4[3] = d;
      lo4[0] = (f16)(f0 - (float)a); lo4[1] = (f16)(f1 - (float)b);
      lo4[2] = (f16)(f2 - (float)cc); lo4[3] = (f16)(f3 - (float)d);
      *(half4_t*)&Ahi[off] = hi4; *(half4_t*)&Alo[off] = lo4;
    }
    __syncthreads();
    MFMA_RANGE(8, KT);
    {
      float4_t C = acc0 + acc1;
      #pragma unroll
      for (int i = 0; i < 4; i++)
        red[(q * 4 + i) * RST + nt * 64 + dq * 16 + l15] = C[i];
    }
    __syncthreads();

    // ---- elementwise (c in VGPR, fast activations), h -> LLC ----
    {
      float ig = red[eb * RST + ed];
      float fg = red[eb * RST + 64 + ed];
      float gg = red[eb * RST + 128 + ed];
      float og = red[eb * RST + 192 + ed];
      float cn = sigmoid_fast(fg) * c_reg + sigmoid_fast(ig) * tanh_fast(gg);
      c_reg = cn;
      llc_store_f32(&hout[(size_t)(r0 + eb) * HDIM + d0 + ed],
                    sigmoid_fast(og) * tanh_fast(cn));
    }
    wait_vm0();       // own h store is in LLC
    __syncthreads();  // whole block's h stores are in LLC

    // ---- flag goes out FIRST (critical path); y-work overlaps the handoff ----
    const int done = t - t_begin + 1;
    const bool do_bar = IS_DEC || t < TT - 1;
    if (do_bar && tid == 0) llc_store_i32(&flags[rt * 8 + jt], done);

    // dec: fused y = fc(h_t) partials (k-split: 16 waves x 1 kt) — AFTER flag.
    if (IS_DEC && jt < 5) {
      float4_t ya = {0.f, 0.f, 0.f, 0.f};
      {
        const int ao = l15 * AST + wv * 32 + q * 8;
        half8_t ahi = *(const half8_t*)&Ahi[ao];
        half8_t alo = *(const half8_t*)&Alo[ao];
        ya = __builtin_amdgcn_mfma_f32_16x16x32_f16(ahi, Fhi, ya, 0, 0, 0);
        ya = __builtin_amdgcn_mfma_f32_16x16x32_f16(alo, Fhi, ya, 0, 0, 0);
        ya = __builtin_amdgcn_mfma_f32_16x16x32_f16(ahi, Flo, ya, 0, 0, 0);
        ya = __builtin_amdgcn_mfma_f32_16x16x32_f16(alo, Flo, ya, 0, 0, 0);
      }
      #pragma unroll
      for (int i = 0; i < 4; i++)
        ypart[wv * 260 + (q * 4 + i) * 16 + l15] = ya[i];
      __syncthreads();  // uniform within block (jt is block-uniform)
      if (tid < 256) {
        float acc = ybias;
        #pragma unroll
        for (int w16 = 0; w16 < 16; w16++) acc += ypart[w16 * 260 + tid];
        recon[(size_t)(r0 + (tid >> 4)) * ROWSTRIDE + (size_t)(t - 1) * DDIM +
              jt * 16 + (tid & 15)] = acc;
      }
    }

    // ---- group barrier: 4-deep pipelined flag poll (8 producers) ----
    if (do_bar) {
      if (tid < 64) poll_flag4(flags + rt * 8 + (tid & 7), done);
      __syncthreads();
    }
  }

  // ---- dec: recon col 255 = fc(h_256 = hA) ----
  if (IS_DEC) {
    if (jt >= 5) return;
    {
      const float4* base =
          (const float4*)(hA + (size_t)r0 * HDIM) + (tid >> 6) * 128 + (tid & 63);
      float4 v0, v1;
      asm volatile(
          "global_load_dwordx4 %0, %2, off sc0 sc1\n\t"
          "global_load_dwordx4 %1, %3, off sc0 sc1\n\t"
          "s_waitcnt vmcnt(0)"
          : "=&v"(v0), "=&v"(v1)
          : "v"(base), "v"(base + 64)
          : "memory");
      __builtin_amdgcn_sched_barrier(0);
      SPLITC(v0, 0); SPLITC(v1, 1);
    }
    __syncthreads();
    {
      float4_t ya = {0.f, 0.f, 0.f, 0.f};
      {
        const int ao = l15 * AST + wv * 32 + q * 8;
        half8_t ahi = *(const half8_t*)&Ahi[ao];
        half8_t alo = *(const half8_t*)&Alo[ao];
        ya = __builtin_amdgcn_mfma_f32_16x16x32_f16(ahi, Fhi, ya, 0, 0, 0);
        ya = __builtin_amdgcn_mfma_f32_16x16x32_f16(alo, Fhi, ya, 0, 0, 0);
        ya = __builtin_amdgcn_mfma_f32_16x16x32_f16(ahi, Flo, ya, 0, 0, 0);
        ya = __builtin_amdgcn_mfma_f32_16x16x32_f16(alo, Flo, ya, 0, 0, 0);
      }
      #pragma unroll
      for (int i = 0; i < 4; i++)
        ypart[wv * 260 + (q * 4 + i) * 16 + l15] = ya[i];
    }
    __syncthreads();
    if (tid < 256) {
      float acc = ybias;
      #pragma unroll
      for (int w16 = 0; w16 < 16; w16++) acc += ypart[w16 * 260 + tid];
      recon[(size_t)(r0 + (tid >> 4)) * ROWSTRIDE + (size_t)255 * DDIM +
            jt * 16 + (tid & 15)] = acc;
    }
  }
  #undef SPLITC
  #undef MFMA_RANGE
}

// ---------------- vector quantizer ----------------------------------------------
__global__ __launch_bounds__(256) void vq_kernel(
    const float* __restrict__ z, const float* __restrict__ emb,
    float* __restrict__ quant, float* __restrict__ vq_part,
    float* __restrict__ out_idx) {
  __shared__ float sz[512];
  __shared__ float sd[256];
  __shared__ int si[256];
  int b = blockIdx.x, tid = threadIdx.x;
  sz[tid] = z[(size_t)b * HDIM + tid];
  sz[tid + 256] = z[(size_t)b * HDIM + 256 + tid];
  __syncthreads();
  float bd = 3.4e38f;
  int bk = 0;
  for (int k = tid; k < 512; k += 256) {
    const float4* e4 = (const float4*)(emb + (size_t)k * HDIM);
    const float4* z4 = (const float4*)sz;
    float dot = 0.f, ee = 0.f;
    #pragma unroll 4
    for (int qq = 0; qq < 128; qq++) {
      float4 ev = e4[qq], zv = z4[qq];
      dot += ev.x * zv.x + ev.y * zv.y + ev.z * zv.z + ev.w * zv.w;
      ee += ev.x * ev.x + ev.y * ev.y + ev.z * ev.z + ev.w * ev.w;
    }
    float dist = ee - 2.f * dot;
    if (dist < bd) { bd = dist; bk = k; }
  }
  sd[tid] = bd; si[tid] = bk;
  __syncthreads();
  for (int s = 128; s > 0; s >>= 1) {
    if (tid < s) {
      float od = sd[tid + s]; int ok = si[tid + s];
      if (od < sd[tid] || (od == sd[tid] && ok < si[tid])) { sd[tid] = od; si[tid] = ok; }
    }
    __syncthreads();
  }
  int kbest = si[0];
  __syncthreads();
  float e0 = emb[(size_t)kbest * HDIM + tid];
  float e1 = emb[(size_t)kbest * HDIM + 256 + tid];
  quant[(size_t)b * HDIM + tid] = e0;
  quant[(size_t)b * HDIM + 256 + tid] = e1;
  float q0 = e0 - sz[tid], q1 = e1 - sz[tid + 256];
  sd[tid] = q0 * q0 + q1 * q1;
  __syncthreads();
  for (int st = 128; st > 0; st >>= 1) {
    if (tid < st) sd[tid] += sd[tid + st];
    __syncthreads();
  }
  if (tid == 0) { vq_part[b] = sd[0]; out_idx[b] = (float)kbest; }
}

__global__ __launch_bounds__(256) void vq_reduce_kernel(const float* __restrict__ vq_part,
                                                        float* __restrict__ out_loss) {
  __shared__ float s[256];
  int tid = threadIdx.x;
  s[tid] = vq_part[tid];
  __syncthreads();
  for (int st = 128; st > 0; st >>= 1) {
    if (tid < st) s[tid] += s[tid + st];
    __syncthreads();
  }
  if (tid == 0) out_loss[0] = s[0] * 1.25f / (float)(BB * HDIM);
}

extern "C" void kernel_launch(void* const* d_in, const int* in_sizes, int n_in,
                              void* d_out, int out_size, void* d_ws, size_t ws_size,
                              hipStream_t stream) {
  const float* traj = (const float*)d_in[0];
  const float* eWih = (const float*)d_in[2];
  const float* eWhh = (const float*)d_in[3];
  const float* eb1  = (const float*)d_in[4];
  const float* eb2  = (const float*)d_in[5];
  const float* emb  = (const float*)d_in[6];
  const float* dWih = (const float*)d_in[7];
  const float* dWhh = (const float*)d_in[8];
  const float* db1  = (const float*)d_in[9];
  const float* db2  = (const float*)d_in[10];
  const float* fcW  = (const float*)d_in[11];
  const float* fcb  = (const float*)d_in[12];

  float* out = (float*)d_out;
  float* recon = out;
  float* out_loss = out + 5242880;
  float* out_idx = out + 5242881;

  float* ws = (float*)d_ws;
  float* hA      = ws + WS_HA;
  float* cD      = ws + WS_CD;
  int*   bar     = (int*)(ws + WS_BAR);
  float* hB      = ws + WS_HB;
  float* quant   = ws + WS_QUANT;
  float* vq_part = ws + WS_VQP;
  float* b_enc   = ws + WS_BENC;
  float* b_dec0  = ws + WS_BDEC0;
  float* b_eff   = ws + WS_BEFF;
  float* W_eff   = ws + WS_WEFF;

  // zero hA, cD, flags
  zero_kernel<<<257, 256, 0, stream>>>((float4*)ws, 65792);
  bias_init_kernel<<<8, 256, 0, stream>>>(eb1, eb2, db1, db2, dWih, fcb,
                                          b_enc, b_dec0, b_eff);
  fold_kernel<<<2048, 256, 0, stream>>>(dWih, dWhh, fcW, W_eff);

  // encoder: t=0..255 persistent; z lands in hA; flags [0..127]
  lstm_persist<0><<<128, 1024, 0, stream>>>(
      eWhh, eWih, b_enc, traj, nullptr, nullptr, nullptr, nullptr, hA, hB, bar);

  vq_kernel<<<256, 256, 0, stream>>>(hA, emb, quant, vq_part, out_idx);
  vq_reduce_kernel<<<1, 256, 0, stream>>>(vq_part, out_loss);

  // decoder t=0 (plain dWhh, x=0): h_1 -> hB, c_1 -> cD
  lstm_step_kernel<<<512, 256, 0, stream>>>(dWhh, b_dec0, quant, cD, hB);
  // decoder t=1..255 persistent with W_eff; recon fused; flags [256..383]
  lstm_persist<1><<<128, 1024, 0, stream>>>(
      W_eff, nullptr, b_eff, nullptr, cD, fcW, fcb, recon, hA, hB, bar + 256);
}

// Round 13
// 2179.276 us; speedup vs baseline: 2.8604x; 2.8604x over previous
//
#include <hip/hip_runtime.h>
#include <math.h>

// B=256, T=256, D=80, H=512, 4H=2048, K=512
#define BB 256
#define TT 256
#define DDIM 80
#define HDIM 512
#define ROWSTRIDE 20480   // T*D

// ws layout (float offsets)
#define WS_HA    0          // 131072 (zeroed: enc h0 / final z)
#define WS_CD    131072     // 131072 (zeroed: dec cell state)
#define WS_BAR   262144     // int flags: enc [0..255], dec [256..511]
#define WS_HB    263168
#define WS_QUANT 394240
#define WS_VQP   525312
#define WS_BENC  525568
#define WS_BDEC0 527616
#define WS_BEFF  529664
#define WS_WEFF  531712     // 2048*512

typedef _Float16 f16;
typedef f16 half4_t __attribute__((ext_vector_type(4)));
typedef f16 half8_t __attribute__((ext_vector_type(8)));
typedef float float4_t __attribute__((ext_vector_type(4)));

// fast gate activations (v_exp_f32 + v_rcp_f32); saturation-safe, |err|~1e-7
__device__ __forceinline__ float sigmoid_fast(float v) {
  return __builtin_amdgcn_rcpf(1.0f + __builtin_amdgcn_exp2f(-1.44269504f * v));
}
__device__ __forceinline__ float tanh_fast(float v) {
  return 2.0f * __builtin_amdgcn_rcpf(1.0f + __builtin_amdgcn_exp2f(-2.88539008f * v)) - 1.0f;
}

// LLC-coherent (bypass L1/L2) primitives
__device__ __forceinline__ void llc_store_f32(float* p, float v) {
  asm volatile("global_store_dword %0, %1, off sc0 sc1" :: "v"(p), "v"(v) : "memory");
}
__device__ __forceinline__ void llc_store_i32(int* p, int v) {
  asm volatile("global_store_dword %0, %1, off sc0 sc1" :: "v"(p), "v"(v) : "memory");
}
__device__ __forceinline__ int llc_load_i32(const int* p) {
  int v;
  asm volatile("global_load_dword %0, %1, off sc0 sc1\n\ts_waitcnt vmcnt(0)"
               : "=v"(v) : "v"(p) : "memory");
  return v;
}
__device__ __forceinline__ void wait_vm0() {
  asm volatile("s_waitcnt vmcnt(0)" ::: "memory");
}

// 4 contiguous LLC dwordx4 loads (one 64B run) + full wait, fused in one asm
// block: outputs written by the block itself -> consumers can't hoist above.
__device__ __forceinline__ void llc_load_64B(
    const float* p, float4& a0, float4& a1, float4& a2, float4& a3) {
  asm volatile(
      "global_load_dwordx4 %0, %4, off sc0 sc1\n\t"
      "global_load_dwordx4 %1, %4, off offset:16 sc0 sc1\n\t"
      "global_load_dwordx4 %2, %4, off offset:32 sc0 sc1\n\t"
      "global_load_dwordx4 %3, %4, off offset:48 sc0 sc1\n\t"
      "s_waitcnt vmcnt(0)"
      : "=&v"(a0), "=&v"(a1), "=&v"(a2), "=&v"(a3)
      : "v"(p)
      : "memory");
}

__global__ __launch_bounds__(256) void zero_kernel(float4* __restrict__ p, int n4) {
  int i = blockIdx.x * 256 + threadIdx.x;
  if (i < n4) p[i] = make_float4(0.f, 0.f, 0.f, 0.f);
}

__global__ __launch_bounds__(256) void bias_init_kernel(
    const float* __restrict__ eb1, const float* __restrict__ eb2,
    const float* __restrict__ db1, const float* __restrict__ db2,
    const float* __restrict__ dWih, const float* __restrict__ fcb,
    float* __restrict__ b_enc, float* __restrict__ b_dec0,
    float* __restrict__ b_eff) {
  int n = blockIdx.x * 256 + threadIdx.x;
  b_enc[n] = eb1[n] + eb2[n];
  float bd = db1[n] + db2[n];
  b_dec0[n] = bd;
  float acc = bd;
  #pragma unroll 16
  for (int d = 0; d < DDIM; d++) acc += dWih[n * DDIM + d] * fcb[d];
  b_eff[n] = acc;
}

// W_eff = dec_W_hh + dec_W_ih @ fc_W  (2048x512, K=80)
__global__ __launch_bounds__(256) void fold_kernel(
    const float* __restrict__ dWih, const float* __restrict__ dWhh,
    const float* __restrict__ fcW, float* __restrict__ W_eff) {
  int n = blockIdx.x;
  int tid = threadIdx.x;
  __shared__ float sw[DDIM];
  if (tid < DDIM) sw[tid] = dWih[n * DDIM + tid];
  __syncthreads();
  for (int k = tid; k < HDIM; k += 256) {
    float acc = dWhh[n * HDIM + k];
    #pragma unroll 16
    for (int d = 0; d < DDIM; d++) acc += sw[d] * fcW[d * HDIM + k];
    W_eff[n * HDIM + k] = acc;
  }
}

// ---------------- single LSTM step (decoder t=0 only; x = 0) ---------------------
__global__ __launch_bounds__(256) void lstm_step_kernel(
    const float* __restrict__ Whh, const float* __restrict__ bias,
    const float* __restrict__ h_in, float* __restrict__ c,
    float* __restrict__ h_out) {
  __shared__ float sh[16][516];
  int tid = threadIdx.x;
  int rt = blockIdx.x & 15, jt = blockIdx.x >> 4;
  int row0 = rt << 4;
  for (int i = tid; i < 2048; i += 256) {
    int r = i >> 7, kq = i & 127;
    float4 v = *(const float4*)(h_in + (size_t)(row0 + r) * HDIM + (kq << 2));
    *(float4*)&sh[r][kq << 2] = v;
  }
  __syncthreads();
  int r = tid & 15, j0 = tid >> 4;
  int j = (jt << 4) + j0;
  float a0 = bias[j], a1 = bias[512 + j], a2 = bias[1024 + j], a3 = bias[1536 + j];
  const float4* w0 = (const float4*)(Whh + (size_t)j * HDIM);
  const float4* w1 = (const float4*)(Whh + (size_t)(512 + j) * HDIM);
  const float4* w2 = (const float4*)(Whh + (size_t)(1024 + j) * HDIM);
  const float4* w3 = (const float4*)(Whh + (size_t)(1536 + j) * HDIM);
  const float4* hv = (const float4*)&sh[r][0];
  #pragma unroll 4
  for (int kq = 0; kq < 128; kq++) {
    float4 h4 = hv[kq];
    float4 q0 = w0[kq], q1 = w1[kq], q2 = w2[kq], q3 = w3[kq];
    a0 += h4.x * q0.x + h4.y * q0.y + h4.z * q0.z + h4.w * q0.w;
    a1 += h4.x * q1.x + h4.y * q1.y + h4.z * q1.z + h4.w * q1.w;
    a2 += h4.x * q2.x + h4.y * q2.y + h4.z * q2.z + h4.w * q2.w;
    a3 += h4.x * q3.x + h4.y * q3.y + h4.z * q3.z + h4.w * q3.w;
  }
  size_t idx = (size_t)(row0 + r) * HDIM + j;
  float cv = c[idx];
  float cn = sigmoid_fast(a1) * cv + sigmoid_fast(a0) * tanh_fast(a2);
  float hn = sigmoid_fast(a3) * tanh_fast(cn);
  c[idx] = cn;
  h_out[idx] = hn;
}

// ---------------- persistent MFMA LSTM (split-fp16, register-stationary W) -------
// 256 blocks (1/CU), 512 threads. Tiling: block (rt=bid&15, jt=bid>>4): rows
// [rt*16,+16), h-dims [jt*32,+32). Waves: dh=wv>>2, nt=wv&3.
// R13 vs verified R11: (1) flag poll fused into staging, PRODUCER-ALIGNED —
// thread (p=tid>>5, w=tid&31) loads 64B from producer p's slice (row w>>1,
// half w&1); one lane per 32-thread cohort spins on flags[p], so each wave
// waits only its 2 producers and loads overlap stragglers; the pre-MFMA
// __syncthreads restores the full barrier (all 16 flags confirmed before any
// h store). End-of-step poll+barrier removed. (2) 3-term split MFMA (drop
// alo*Wlo, ~2^-22 relative). Fast activations, flag-first, dec-y-after-flag
// kept from R11.
template <int IS_DEC>
__global__ __launch_bounds__(512, 2) void lstm_persist(
    const float* __restrict__ W,      // enc: eWhh; dec: W_eff  [2048][512]
    const float* __restrict__ Wih,    // enc only [2048][80]
    const float* __restrict__ bias,   // [2048]
    const float* __restrict__ traj,   // enc only
    const float* __restrict__ c_init, // dec: cD (holds c_1)
    const float* __restrict__ fcW, const float* __restrict__ fcb,
    float* __restrict__ recon,
    float* __restrict__ hA, float* __restrict__ hB,
    int* __restrict__ flags) {
  constexpr int KT  = IS_DEC ? 16 : 19;    // k-tiles of 32 (enc: 512 h + 80 x + pad)
  constexpr int AST = IS_DEC ? 520 : 616;  // f16 row stride (16B aligned)
  constexpr int RST = 132;                 // red row stride (floats)
  __shared__ f16 Ahi[16 * AST];
  __shared__ f16 Alo[16 * AST];
  __shared__ float red[16 * RST];          // gates: 16 rows x 128 cols
  __shared__ float ypart[IS_DEC ? 8 * 260 : 4];

  const int tid = threadIdx.x;
  const int bid = blockIdx.x;
  const int rt = bid & 15, jt = bid >> 4;
  const int r0 = rt * 16, d0 = jt * 32;
  const int wv = __builtin_amdgcn_readfirstlane(tid >> 6);
  const int l15 = tid & 15;
  const int q = (tid >> 4) & 3;            // quad within wave
  const int dh = wv >> 2, nt = wv & 3;     // dim-half, gate type

  // producer-aligned staging map: thread -> producer sp, row sr, 16-float half
  const int sp = tid >> 5;                 // producer jt index 0..15
  const int sr = (tid & 31) >> 1;          // row 0..15
  const int scol = sp * 32 + (tid & 1) * 16;  // float col base (64B run)

  // stage one float4 at (row sr, col scol+4*i) into split-fp16 LDS
  #define SPLITC(vv, i) { \
    int off = sr * AST + scol + (i) * 4; \
    half4_t hi4, lo4; \
    float f0 = vv.x, f1 = vv.y, f2 = vv.z, f3 = vv.w; \
    f16 a = (f16)f0, b = (f16)f1, cc = (f16)f2, d = (f16)f3; \
    hi4[0] = a; hi4[1] = b; hi4[2] = cc; hi4[3] = d; \
    lo4[0] = (f16)(f0 - (float)a); lo4[1] = (f16)(f1 - (float)b); \
    lo4[2] = (f16)(f2 - (float)cc); lo4[3] = (f16)(f3 - (float)d); \
    *(half4_t*)&Ahi[off] = hi4; *(half4_t*)&Alo[off] = lo4; }

  // ---- register-stationary W: split-fp16 B-fragments ----
  const int grow = nt * 512 + d0 + dh * 16 + l15;  // global gate row
  half8_t Whi[KT], Wlo[KT];
  #pragma unroll
  for (int kt = 0; kt < KT; kt++) {
    #pragma unroll
    for (int j = 0; j < 8; j++) {
      int k = kt * 32 + q * 8 + j;
      float w;
      if (k < 512) w = W[(size_t)grow * HDIM + k];
      else {
        int kx = k - 512;
        w = (!IS_DEC && kx < DDIM) ? Wih[(size_t)grow * DDIM + kx] : 0.f;
      }
      f16 hi = (f16)w;
      Whi[kt][j] = hi;
      Wlo[kt][j] = (f16)(w - (float)hi);
    }
  }
  const float breg = bias[grow];

  // dec: fcW fragments for fused y (jt<5 covers 80 dims; k-split by wave)
  half8_t Fhi[2], Flo[2];
  float ybias = 0.f;
  if (IS_DEC && jt < 5) {
    const int drow = jt * 16 + l15;
    #pragma unroll
    for (int kk = 0; kk < 2; kk++) {
      const int kt = wv * 2 + kk;
      #pragma unroll
      for (int j = 0; j < 8; j++) {
        float w = fcW[(size_t)drow * HDIM + kt * 32 + q * 8 + j];
        f16 hi = (f16)w;
        Fhi[kk][j] = hi;
        Flo[kk][j] = (f16)(w - (float)hi);
      }
    }
    ybias = fcb[jt * 16 + l15];
  }

  const int eb = tid >> 5, ed = tid & 31;  // elementwise (row, dim)
  float c_reg = IS_DEC ? c_init[(size_t)(r0 + eb) * HDIM + d0 + ed] : 0.f;
  __syncthreads();

  // 3-term split-fp16 MFMA (alo*Wlo dropped: ~2^-22 relative)
  #define MFMA_RANGE(LO, HI) { \
    _Pragma("unroll") \
    for (int kt = (LO); kt < (HI); kt++) { \
      half8_t ahi = *(const half8_t*)&Ahi[abase + kt * 32]; \
      half8_t alo = *(const half8_t*)&Alo[abase + kt * 32]; \
      if (kt & 1) { \
        acc1 = __builtin_amdgcn_mfma_f32_16x16x32_f16(ahi, Whi[kt], acc1, 0, 0, 0); \
        acc1 = __builtin_amdgcn_mfma_f32_16x16x32_f16(alo, Whi[kt], acc1, 0, 0, 0); \
        acc1 = __builtin_amdgcn_mfma_f32_16x16x32_f16(ahi, Wlo[kt], acc1, 0, 0, 0); \
      } else { \
        acc0 = __builtin_amdgcn_mfma_f32_16x16x32_f16(ahi, Whi[kt], acc0, 0, 0, 0); \
        acc0 = __builtin_amdgcn_mfma_f32_16x16x32_f16(alo, Whi[kt], acc0, 0, 0, 0); \
        acc0 = __builtin_amdgcn_mfma_f32_16x16x32_f16(ahi, Wlo[kt], acc0, 0, 0, 0); \
      } \
    } }

  const int t_begin = IS_DEC ? 1 : 0;
  for (int t = t_begin; t < TT; t++) {
    const float* hin = (t & 1) ? hB : hA;
    float* hout = (t & 1) ? hA : hB;

    // ---- enc: x tile -> LDS (plain cached loads; independent of h) ----
    if (!IS_DEC && tid < 384) {   // 16 rows x 24 quads (cols 512..608, pad>592)
      int row = tid / 24, c4 = tid % 24;
      float4 v = (c4 < 20)
          ? *(const float4*)(traj + (size_t)(r0 + row) * ROWSTRIDE +
                             (size_t)t * DDIM + c4 * 4)
          : make_float4(0.f, 0.f, 0.f, 0.f);
      int off = row * AST + 512 + c4 * 4;
      half4_t hi4, lo4;
      float f0 = v.x, f1 = v.y, f2 = v.z, f3 = v.w;
      f16 a = (f16)f0, b = (f16)f1, cc = (f16)f2, d = (f16)f3;
      hi4[0] = a; hi4[1] = b; hi4[2] = cc; hi4[3] = d;
      lo4[0] = (f16)(f0 - (float)a); lo4[1] = (f16)(f1 - (float)b);
      lo4[2] = (f16)(f2 - (float)cc); lo4[3] = (f16)(f3 - (float)d);
      *(half4_t*)&Ahi[off] = hi4; *(half4_t*)&Alo[off] = lo4;
    }

    // ---- stage h: per-cohort poll of OWN producer's flag, then 64B load ----
    // thr = t - t_begin = producer flag value after they completed step t-1
    // (t==t_begin: thr 0 -> no wait; enc t=0 reads zeroed hA = h0).
    {
      const int thr = t - t_begin;
      if (thr > 0 && (tid & 31) == 0) {
        const int* fp = flags + rt * 16 + sp;
        while (llc_load_i32(fp) < thr) {}
      }
      // whole wave proceeds only after its cohort lanes exit the spin
      const float* hp = hin + (size_t)(r0 + sr) * HDIM + scol;
      float4 v0, v1, v2, v3;
      llc_load_64B(hp, v0, v1, v2, v3);
      __builtin_amdgcn_sched_barrier(0);   // rule #18: SPLITC stays below the wait
      SPLITC(v0, 0); SPLITC(v1, 1); SPLITC(v2, 2); SPLITC(v3, 3);
    }
    __syncthreads();  // full barrier: all 16 producers confirmed + staged

    // ---- gates: 3-term split-fp16 MFMA, full K per wave ----
    float4_t acc0 = {breg, breg, breg, breg};
    float4_t acc1 = {0.f, 0.f, 0.f, 0.f};
    const int abase = l15 * AST + q * 8;
    MFMA_RANGE(0, KT);
    {
      float4_t C = acc0 + acc1;
      #pragma unroll
      for (int i = 0; i < 4; i++)
        red[(q * 4 + i) * RST + nt * 32 + dh * 16 + l15] = C[i];
    }
    __syncthreads();

    // ---- elementwise (c in VGPR, fast activations), h -> LLC ----
    {
      float ig = red[eb * RST + ed];
      float fg = red[eb * RST + 32 + ed];
      float gg = red[eb * RST + 64 + ed];
      float og = red[eb * RST + 96 + ed];
      float cn = sigmoid_fast(fg) * c_reg + sigmoid_fast(ig) * tanh_fast(gg);
      c_reg = cn;
      llc_store_f32(&hout[(size_t)(r0 + eb) * HDIM + d0 + ed],
                    sigmoid_fast(og) * tanh_fast(cn));
    }
    wait_vm0();       // own h store is in LLC
    __syncthreads();  // whole block's h stores are in LLC

    // ---- flag goes out FIRST (critical path); y-work overlaps the handoff ----
    const int done = t - t_begin + 1;
    if ((IS_DEC || t < TT - 1) && tid == 0)
      llc_store_i32(&flags[rt * 16 + jt], done);

    // dec: fused y = fc(h_t) partials (k-split across waves) — AFTER flag.
    if (IS_DEC && jt < 5) {
      float4_t ya = {0.f, 0.f, 0.f, 0.f};
      #pragma unroll
      for (int kk = 0; kk < 2; kk++) {
        const int kt = wv * 2 + kk;
        const int ao = l15 * AST + kt * 32 + q * 8;
        half8_t ahi = *(const half8_t*)&Ahi[ao];
        half8_t alo = *(const half8_t*)&Alo[ao];
        ya = __builtin_amdgcn_mfma_f32_16x16x32_f16(ahi, Fhi[kk], ya, 0, 0, 0);
        ya = __builtin_amdgcn_mfma_f32_16x16x32_f16(alo, Fhi[kk], ya, 0, 0, 0);
        ya = __builtin_amdgcn_mfma_f32_16x16x32_f16(ahi, Flo[kk], ya, 0, 0, 0);
        ya = __builtin_amdgcn_mfma_f32_16x16x32_f16(alo, Flo[kk], ya, 0, 0, 0);
      }
      #pragma unroll
      for (int i = 0; i < 4; i++)
        ypart[wv * 260 + (q * 4 + i) * 16 + l15] = ya[i];
      __syncthreads();  // uniform within block (jt is block-uniform)
      if (tid < 256) {
        float acc = ybias;
        #pragma unroll
        for (int w8 = 0; w8 < 8; w8++) acc += ypart[w8 * 260 + tid];
        recon[(size_t)(r0 + (tid >> 4)) * ROWSTRIDE + (size_t)(t - 1) * DDIM +
              jt * 16 + (tid & 15)] = acc;
      }
    }
    // no trailing poll: next iteration's staging polls per-producer.
  }

  // ---- dec: recon col 255 = fc(h_256 = hA), poll thr=255 then load ----
  if (IS_DEC) {
    if (jt >= 5) return;
    {
      if ((tid & 31) == 0) {
        const int* fp = flags + rt * 16 + sp;
        while (llc_load_i32(fp) < 255) {}
      }
      const float* hp = hA + (size_t)(r0 + sr) * HDIM + scol;
      float4 v0, v1, v2, v3;
      llc_load_64B(hp, v0, v1, v2, v3);
      __builtin_amdgcn_sched_barrier(0);
      SPLITC(v0, 0); SPLITC(v1, 1); SPLITC(v2, 2); SPLITC(v3, 3);
    }
    __syncthreads();
    {
      float4_t ya = {0.f, 0.f, 0.f, 0.f};
      #pragma unroll
      for (int kk = 0; kk < 2; kk++) {
        const int kt = wv * 2 + kk;
        const int ao = l15 * AST + kt * 32 + q * 8;
        half8_t ahi = *(const half8_t*)&Ahi[ao];
        half8_t alo = *(const half8_t*)&Alo[ao];
        ya = __builtin_amdgcn_mfma_f32_16x16x32_f16(ahi, Fhi[kk], ya, 0, 0, 0);
        ya = __builtin_amdgcn_mfma_f32_16x16x32_f16(alo, Fhi[kk], ya, 0, 0, 0);
        ya = __builtin_amdgcn_mfma_f32_16x16x32_f16(ahi, Flo[kk], ya, 0, 0, 0);
        ya = __builtin_amdgcn_mfma_f32_16x16x32_f16(alo, Flo[kk], ya, 0, 0, 0);
      }
      #pragma unroll
      for (int i = 0; i < 4; i++)
        ypart[wv * 260 + (q * 4 + i) * 16 + l15] = ya[i];
    }
    __syncthreads();
    if (tid < 256) {
      float acc = ybias;
      #pragma unroll
      for (int w8 = 0; w8 < 8; w8++) acc += ypart[w8 * 260 + tid];
      recon[(size_t)(r0 + (tid >> 4)) * ROWSTRIDE + (size_t)255 * DDIM +
            jt * 16 + (tid & 15)] = acc;
    }
  }
  #undef SPLITC
  #undef MFMA_RANGE
}

// ---------------- vector quantizer ----------------------------------------------
__global__ __launch_bounds__(256) void vq_kernel(
    const float* __restrict__ z, const float* __restrict__ emb,
    float* __restrict__ quant, float* __restrict__ vq_part,
    float* __restrict__ out_idx) {
  __shared__ float sz[512];
  __shared__ float sd[256];
  __shared__ int si[256];
  int b = blockIdx.x, tid = threadIdx.x;
  sz[tid] = z[(size_t)b * HDIM + tid];
  sz[tid + 256] = z[(size_t)b * HDIM + 256 + tid];
  __syncthreads();
  float bd = 3.4e38f;
  int bk = 0;
  for (int k = tid; k < 512; k += 256) {
    const float4* e4 = (const float4*)(emb + (size_t)k * HDIM);
    const float4* z4 = (const float4*)sz;
    float dot = 0.f, ee = 0.f;
    #pragma unroll 4
    for (int qq = 0; qq < 128; qq++) {
      float4 ev = e4[qq], zv = z4[qq];
      dot += ev.x * zv.x + ev.y * zv.y + ev.z * zv.z + ev.w * zv.w;
      ee += ev.x * ev.x + ev.y * ev.y + ev.z * ev.z + ev.w * ev.w;
    }
    float dist = ee - 2.f * dot;
    if (dist < bd) { bd = dist; bk = k; }
  }
  sd[tid] = bd; si[tid] = bk;
  __syncthreads();
  for (int s = 128; s > 0; s >>= 1) {
    if (tid < s) {
      float od = sd[tid + s]; int ok = si[tid + s];
      if (od < sd[tid] || (od == sd[tid] && ok < si[tid])) { sd[tid] = od; si[tid] = ok; }
    }
    __syncthreads();
  }
  int kbest = si[0];
  __syncthreads();
  float e0 = emb[(size_t)kbest * HDIM + tid];
  float e1 = emb[(size_t)kbest * HDIM + 256 + tid];
  quant[(size_t)b * HDIM + tid] = e0;
  quant[(size_t)b * HDIM + 256 + tid] = e1;
  float q0 = e0 - sz[tid], q1 = e1 - sz[tid + 256];
  sd[tid] = q0 * q0 + q1 * q1;
  __syncthreads();
  for (int st = 128; st > 0; st >>= 1) {
    if (tid < st) sd[tid] += sd[tid + st];
    __syncthreads();
  }
  if (tid == 0) { vq_part[b] = sd[0]; out_idx[b] = (float)kbest; }
}

__global__ __launch_bounds__(256) void vq_reduce_kernel(const float* __restrict__ vq_part,
                                                        float* __restrict__ out_loss) {
  __shared__ float s[256];
  int tid = threadIdx.x;
  s[tid] = vq_part[tid];
  __syncthreads();
  for (int st = 128; st > 0; st >>= 1) {
    if (tid < st) s[tid] += s[tid + st];
    __syncthreads();
  }
  if (tid == 0) out_loss[0] = s[0] * 1.25f / (float)(BB * HDIM);
}

extern "C" void kernel_launch(void* const* d_in, const int* in_sizes, int n_in,
                              void* d_out, int out_size, void* d_ws, size_t ws_size,
                              hipStream_t stream) {
  const float* traj = (const float*)d_in[0];
  const float* eWih = (const float*)d_in[2];
  const float* eWhh = (const float*)d_in[3];
  const float* eb1  = (const float*)d_in[4];
  const float* eb2  = (const float*)d_in[5];
  const float* emb  = (const float*)d_in[6];
  const float* dWih = (const float*)d_in[7];
  const float* dWhh = (const float*)d_in[8];
  const float* db1  = (const float*)d_in[9];
  const float* db2  = (const float*)d_in[10];
  const float* fcW  = (const float*)d_in[11];
  const float* fcb  = (const float*)d_in[12];

  float* out = (float*)d_out;
  float* recon = out;
  float* out_loss = out + 5242880;
  float* out_idx = out + 5242881;

  float* ws = (float*)d_ws;
  float* hA      = ws + WS_HA;
  float* cD      = ws + WS_CD;
  int*   bar     = (int*)(ws + WS_BAR);
  float* hB      = ws + WS_HB;
  float* quant   = ws + WS_QUANT;
  float* vq_part = ws + WS_VQP;
  float* b_enc   = ws + WS_BENC;
  float* b_dec0  = ws + WS_BDEC0;
  float* b_eff   = ws + WS_BEFF;
  float* W_eff   = ws + WS_WEFF;

  // zero hA, cD, flags
  zero_kernel<<<257, 256, 0, stream>>>((float4*)ws, 65792);
  bias_init_kernel<<<8, 256, 0, stream>>>(eb1, eb2, db1, db2, dWih, fcb,
                                          b_enc, b_dec0, b_eff);
  fold_kernel<<<2048, 256, 0, stream>>>(dWih, dWhh, fcW, W_eff);

  // encoder: t=0..255 persistent; z lands in hA; flags [0..255]
  lstm_persist<0><<<256, 512, 0, stream>>>(
      eWhh, eWih, b_enc, traj, nullptr, nullptr, nullptr, nullptr, hA, hB, bar);

  vq_kernel<<<256, 256, 0, stream>>>(hA, emb, quant, vq_part, out_idx);
  vq_reduce_kernel<<<1, 256, 0, stream>>>(vq_part, out_loss);

  // decoder t=0 (plain dWhh, x=0): h_1 -> hB, c_1 -> cD
  lstm_step_kernel<<<512, 256, 0, stream>>>(dWhh, b_dec0, quant, cD, hB);
  // decoder t=1..255 persistent with W_eff; recon fused; flags [256..511]
  lstm_persist<1><<<256, 512, 0, stream>>>(
      W_eff, nullptr, b_eff, nullptr, cD, fcW, fcb, recon, hA, hB, bar + 256);
}

// Round 14
// 1879.056 us; speedup vs baseline: 3.3174x; 1.1598x over previous
//
#include <hip/hip_runtime.h>
#include <math.h>

// B=256, T=256, D=80, H=512, 4H=2048, K=512
#define BB 256
#define TT 256
#define DDIM 80
#define HDIM 512
#define ROWSTRIDE 20480   // T*D

// ws layout (float offsets)
#define WS_HA    0          // 131072 (zeroed: enc h0 / final z)
#define WS_CD    131072     // 131072 (zeroed: dec cell state)
#define WS_BAR   262144     // int flags: enc [0..255], dec [256..511]
#define WS_HB    263168
#define WS_QUANT 394240
#define WS_VQP   525312
#define WS_BENC  525568
#define WS_BDEC0 527616
#define WS_BEFF  529664
#define WS_WEFF  531712     // 2048*512

typedef _Float16 f16;
typedef f16 half4_t __attribute__((ext_vector_type(4)));
typedef f16 half8_t __attribute__((ext_vector_type(8)));
typedef float float4_t __attribute__((ext_vector_type(4)));

// fast gate activations (v_exp_f32 + v_rcp_f32); saturation-safe, |err|~1e-7
__device__ __forceinline__ float sigmoid_fast(float v) {
  return __builtin_amdgcn_rcpf(1.0f + __builtin_amdgcn_exp2f(-1.44269504f * v));
}
__device__ __forceinline__ float tanh_fast(float v) {
  return 2.0f * __builtin_amdgcn_rcpf(1.0f + __builtin_amdgcn_exp2f(-2.88539008f * v)) - 1.0f;
}

// LLC-coherent (bypass L1/L2) primitives
__device__ __forceinline__ void llc_store_f32(float* p, float v) {
  asm volatile("global_store_dword %0, %1, off sc0 sc1" :: "v"(p), "v"(v) : "memory");
}
__device__ __forceinline__ void llc_store_i32(int* p, int v) {
  asm volatile("global_store_dword %0, %1, off sc0 sc1" :: "v"(p), "v"(v) : "memory");
}
__device__ __forceinline__ void wait_vm0() {
  asm volatile("s_waitcnt vmcnt(0)" ::: "memory");
}

// 4-deep pipelined flag poll (sampling period ~RT/4); wave-uniform exit via
// vcc; vmcnt(0) drain on exit keeps later counted waits correct.
__device__ __forceinline__ void poll_flag4(const int* fp, int done) {
  int a0, a1, a2, a3;
  asm volatile(
      "global_load_dword %0, %4, off sc0 sc1\n\t"
      "global_load_dword %1, %4, off sc0 sc1\n\t"
      "global_load_dword %2, %4, off sc0 sc1\n\t"
      "Lpoll%=:\n\t"
      "global_load_dword %3, %4, off sc0 sc1\n\t"
      "s_waitcnt vmcnt(3)\n\t"
      "v_cmp_gt_i32 vcc, %5, %0\n\t"
      "s_cbranch_vccz Ldone%=\n\t"
      "global_load_dword %0, %4, off sc0 sc1\n\t"
      "s_waitcnt vmcnt(3)\n\t"
      "v_cmp_gt_i32 vcc, %5, %1\n\t"
      "s_cbranch_vccz Ldone%=\n\t"
      "global_load_dword %1, %4, off sc0 sc1\n\t"
      "s_waitcnt vmcnt(3)\n\t"
      "v_cmp_gt_i32 vcc, %5, %2\n\t"
      "s_cbranch_vccz Ldone%=\n\t"
      "global_load_dword %2, %4, off sc0 sc1\n\t"
      "s_waitcnt vmcnt(3)\n\t"
      "v_cmp_gt_i32 vcc, %5, %3\n\t"
      "s_cbranch_vccnz Lpoll%=\n\t"
      "Ldone%=:\n\t"
      "s_waitcnt vmcnt(0)"
      : "=&v"(a0), "=&v"(a1), "=&v"(a2), "=&v"(a3)
      : "v"(fp), "s"(done)
      : "vcc", "memory");
}

// 4 LLC loads + full wait fused in one asm block (outputs written by the block
// itself -> no consumer can be hoisted before the wait). Used on cold paths.
__device__ __forceinline__ void llc_load_4xf4_cols(
    const float4* base,
    float4& a0, float4& a1, float4& a2, float4& a3) {
  asm volatile(
      "global_load_dwordx4 %0, %4, off sc0 sc1\n\t"
      "global_load_dwordx4 %1, %5, off sc0 sc1\n\t"
      "global_load_dwordx4 %2, %6, off sc0 sc1\n\t"
      "global_load_dwordx4 %3, %7, off sc0 sc1\n\t"
      "s_waitcnt vmcnt(0)"
      : "=&v"(a0), "=&v"(a1), "=&v"(a2), "=&v"(a3)
      : "v"(base), "v"(base + 32), "v"(base + 64), "v"(base + 96)
      : "memory");
}

__global__ __launch_bounds__(256) void zero_kernel(float4* __restrict__ p, int n4) {
  int i = blockIdx.x * 256 + threadIdx.x;
  if (i < n4) p[i] = make_float4(0.f, 0.f, 0.f, 0.f);
}

__global__ __launch_bounds__(256) void bias_init_kernel(
    const float* __restrict__ eb1, const float* __restrict__ eb2,
    const float* __restrict__ db1, const float* __restrict__ db2,
    const float* __restrict__ dWih, const float* __restrict__ fcb,
    float* __restrict__ b_enc, float* __restrict__ b_dec0,
    float* __restrict__ b_eff) {
  int n = blockIdx.x * 256 + threadIdx.x;
  b_enc[n] = eb1[n] + eb2[n];
  float bd = db1[n] + db2[n];
  b_dec0[n] = bd;
  float acc = bd;
  #pragma unroll 16
  for (int d = 0; d < DDIM; d++) acc += dWih[n * DDIM + d] * fcb[d];
  b_eff[n] = acc;
}

// W_eff = dec_W_hh + dec_W_ih @ fc_W  (2048x512, K=80)
__global__ __launch_bounds__(256) void fold_kernel(
    const float* __restrict__ dWih, const float* __restrict__ dWhh,
    const float* __restrict__ fcW, float* __restrict__ W_eff) {
  int n = blockIdx.x;
  int tid = threadIdx.x;
  __shared__ float sw[DDIM];
  if (tid < DDIM) sw[tid] = dWih[n * DDIM + tid];
  __syncthreads();
  for (int k = tid; k < HDIM; k += 256) {
    float acc = dWhh[n * HDIM + k];
    #pragma unroll 16
    for (int d = 0; d < DDIM; d++) acc += sw[d] * fcW[d * HDIM + k];
    W_eff[n * HDIM + k] = acc;
  }
}

// ---------------- single LSTM step (decoder t=0 only; x = 0) ---------------------
__global__ __launch_bounds__(256) void lstm_step_kernel(
    const float* __restrict__ Whh, const float* __restrict__ bias,
    const float* __restrict__ h_in, float* __restrict__ c,
    float* __restrict__ h_out) {
  __shared__ float sh[16][516];
  int tid = threadIdx.x;
  int rt = blockIdx.x & 15, jt = blockIdx.x >> 4;
  int row0 = rt << 4;
  for (int i = tid; i < 2048; i += 256) {
    int r = i >> 7, kq = i & 127;
    float4 v = *(const float4*)(h_in + (size_t)(row0 + r) * HDIM + (kq << 2));
    *(float4*)&sh[r][kq << 2] = v;
  }
  __syncthreads();
  int r = tid & 15, j0 = tid >> 4;
  int j = (jt << 4) + j0;
  float a0 = bias[j], a1 = bias[512 + j], a2 = bias[1024 + j], a3 = bias[1536 + j];
  const float4* w0 = (const float4*)(Whh + (size_t)j * HDIM);
  const float4* w1 = (const float4*)(Whh + (size_t)(512 + j) * HDIM);
  const float4* w2 = (const float4*)(Whh + (size_t)(1024 + j) * HDIM);
  const float4* w3 = (const float4*)(Whh + (size_t)(1536 + j) * HDIM);
  const float4* hv = (const float4*)&sh[r][0];
  #pragma unroll 4
  for (int kq = 0; kq < 128; kq++) {
    float4 h4 = hv[kq];
    float4 q0 = w0[kq], q1 = w1[kq], q2 = w2[kq], q3 = w3[kq];
    a0 += h4.x * q0.x + h4.y * q0.y + h4.z * q0.z + h4.w * q0.w;
    a1 += h4.x * q1.x + h4.y * q1.y + h4.z * q1.z + h4.w * q1.w;
    a2 += h4.x * q2.x + h4.y * q2.y + h4.z * q2.z + h4.w * q2.w;
    a3 += h4.x * q3.x + h4.y * q3.y + h4.z * q3.z + h4.w * q3.w;
  }
  size_t idx = (size_t)(row0 + r) * HDIM + j;
  float cv = c[idx];
  float cn = sigmoid_fast(a1) * cv + sigmoid_fast(a0) * tanh_fast(a2);
  float hn = sigmoid_fast(a3) * tanh_fast(cn);
  c[idx] = cn;
  h_out[idx] = hn;
}

// ---------------- persistent MFMA LSTM (split-fp16, register-stationary W) -------
// 256 blocks (1/CU), 512 threads. Tiling: block (rt=bid&15, jt=bid>>4): rows
// [rt*16,+16), h-dims [jt*32,+32) -> 128 gate rows. Waves: dh=wv>>2, nt=wv&3.
// R14 = verified R11 structure (fast activations, 4-deep pipelined flag poll,
// flag-first + dec-y-after-flag, split-K staging with rule-#18 fences) with
// ONE change: 3-term split MFMA (drop alo*Wlo, ~2^-22 relative — verified
// harmless in R13's absmax).
template <int IS_DEC>
__global__ __launch_bounds__(512, 2) void lstm_persist(
    const float* __restrict__ W,      // enc: eWhh; dec: W_eff  [2048][512]
    const float* __restrict__ Wih,    // enc only [2048][80]
    const float* __restrict__ bias,   // [2048]
    const float* __restrict__ traj,   // enc only
    const float* __restrict__ c_init, // dec: cD (holds c_1)
    const float* __restrict__ fcW, const float* __restrict__ fcb,
    float* __restrict__ recon,
    float* __restrict__ hA, float* __restrict__ hB,
    int* __restrict__ flags) {
  constexpr int KT  = IS_DEC ? 16 : 19;    // k-tiles of 32 (enc: 512 h + 80 x + pad)
  constexpr int AST = IS_DEC ? 520 : 616;  // f16 row stride (16B aligned)
  constexpr int RST = 132;                 // red row stride (floats)
  __shared__ f16 Ahi[16 * AST];
  __shared__ f16 Alo[16 * AST];
  __shared__ float red[16 * RST];          // gates: 16 rows x 128 cols
  __shared__ float ypart[IS_DEC ? 8 * 260 : 4];

  const int tid = threadIdx.x;
  const int bid = blockIdx.x;
  const int rt = bid & 15, jt = bid >> 4;
  const int r0 = rt * 16, d0 = jt * 32;
  const int wv = __builtin_amdgcn_readfirstlane(tid >> 6);
  const int l15 = tid & 15;
  const int q = (tid >> 4) & 3;            // quad within wave
  const int dh = wv >> 2, nt = wv & 3;     // dim-half, gate type

  // stage one float4 (column-split map) into split-fp16 LDS
  #define SPLITC(vv, k) { \
    int off = (tid >> 5) * AST + (((tid & 31) + (k) * 32) << 2); \
    half4_t hi4, lo4; \
    float f0 = vv.x, f1 = vv.y, f2 = vv.z, f3 = vv.w; \
    f16 a = (f16)f0, b = (f16)f1, cc = (f16)f2, d = (f16)f3; \
    hi4[0] = a; hi4[1] = b; hi4[2] = cc; hi4[3] = d; \
    lo4[0] = (f16)(f0 - (float)a); lo4[1] = (f16)(f1 - (float)b); \
    lo4[2] = (f16)(f2 - (float)cc); lo4[3] = (f16)(f3 - (float)d); \
    *(half4_t*)&Ahi[off] = hi4; *(half4_t*)&Alo[off] = lo4; }

  // ---- register-stationary W: split-fp16 B-fragments ----
  const int grow = nt * 512 + d0 + dh * 16 + l15;  // global gate row
  half8_t Whi[KT], Wlo[KT];
  #pragma unroll
  for (int kt = 0; kt < KT; kt++) {
    #pragma unroll
    for (int j = 0; j < 8; j++) {
      int k = kt * 32 + q * 8 + j;
      float w;
      if (k < 512) w = W[(size_t)grow * HDIM + k];
      else {
        int kx = k - 512;
        w = (!IS_DEC && kx < DDIM) ? Wih[(size_t)grow * DDIM + kx] : 0.f;
      }
      f16 hi = (f16)w;
      Whi[kt][j] = hi;
      Wlo[kt][j] = (f16)(w - (float)hi);
    }
  }
  const float breg = bias[grow];

  // dec: fcW fragments for fused y (jt<5 covers 80 dims; k-split by wave)
  half8_t Fhi[2], Flo[2];
  float ybias = 0.f;
  if (IS_DEC && jt < 5) {
    const int drow = jt * 16 + l15;
    #pragma unroll
    for (int kk = 0; kk < 2; kk++) {
      const int kt = wv * 2 + kk;
      #pragma unroll
      for (int j = 0; j < 8; j++) {
        float w = fcW[(size_t)drow * HDIM + kt * 32 + q * 8 + j];
        f16 hi = (f16)w;
        Fhi[kk][j] = hi;
        Flo[kk][j] = (f16)(w - (float)hi);
      }
    }
    ybias = fcb[jt * 16 + l15];
  }

  const int eb = tid >> 5, ed = tid & 31;  // elementwise (row, dim)
  float c_reg = IS_DEC ? c_init[(size_t)(r0 + eb) * HDIM + d0 + ed] : 0.f;
  __syncthreads();

  // 3-term split-fp16 MFMA (alo*Wlo dropped: ~2^-22 relative)
  #define MFMA_RANGE(LO, HI) { \
    _Pragma("unroll") \
    for (int kt = (LO); kt < (HI); kt++) { \
      half8_t ahi = *(const half8_t*)&Ahi[abase + kt * 32]; \
      half8_t alo = *(const half8_t*)&Alo[abase + kt * 32]; \
      if (kt & 1) { \
        acc1 = __builtin_amdgcn_mfma_f32_16x16x32_f16(ahi, Whi[kt], acc1, 0, 0, 0); \
        acc1 = __builtin_amdgcn_mfma_f32_16x16x32_f16(alo, Whi[kt], acc1, 0, 0, 0); \
        acc1 = __builtin_amdgcn_mfma_f32_16x16x32_f16(ahi, Wlo[kt], acc1, 0, 0, 0); \
      } else { \
        acc0 = __builtin_amdgcn_mfma_f32_16x16x32_f16(ahi, Whi[kt], acc0, 0, 0, 0); \
        acc0 = __builtin_amdgcn_mfma_f32_16x16x32_f16(alo, Whi[kt], acc0, 0, 0, 0); \
        acc0 = __builtin_amdgcn_mfma_f32_16x16x32_f16(ahi, Wlo[kt], acc0, 0, 0, 0); \
      } \
    } }

  const int t_begin = IS_DEC ? 1 : 0;
  for (int t = t_begin; t < TT; t++) {
    const float* hin = (t & 1) ? hB : hA;
    float* hout = (t & 1) ? hA : hB;

    // ---- enc: issue x prefetch FIRST (plain cached load; counted by the
    //      vmcnt(2) below, so it drains under the h LLC round trip) ----
    float4 xv0;
    if (!IS_DEC && tid < 384) {   // 16 rows x 24 quads (cols 512..608, pad>592)
      int row = tid / 24, c4 = tid % 24;
      xv0 = (c4 < 20)
          ? *(const float4*)(traj + (size_t)(r0 + row) * ROWSTRIDE +
                             (size_t)t * DDIM + c4 * 4)
          : make_float4(0.f, 0.f, 0.f, 0.f);
    }

    // ---- phase 1: issue all 4 h loads; vmcnt(2) fence; stage cols 0..255 ----
    float4 v0, v1, v2, v3;
    const float4* base =
        (const float4*)(hin + (size_t)r0 * HDIM) + (tid >> 5) * 128 + (tid & 31);
    const bool is_t0 = (!IS_DEC && t == 0);
    if (!is_t0) {
      asm volatile(
          "global_load_dwordx4 %0, %4, off sc0 sc1\n\t"
          "global_load_dwordx4 %1, %5, off sc0 sc1\n\t"
          "global_load_dwordx4 %2, %6, off sc0 sc1\n\t"
          "global_load_dwordx4 %3, %7, off sc0 sc1"
          : "=&v"(v0), "=&v"(v1), "=&v"(v2), "=&v"(v3)
          : "v"(base), "v"(base + 32), "v"(base + 64), "v"(base + 96)
          : "memory");
      asm volatile("s_waitcnt vmcnt(2)" ::: "memory");
      __builtin_amdgcn_sched_barrier(0);   // rule #18: no hoisting above the wait
      SPLITC(v0, 0); SPLITC(v1, 1);
    } else {
      // enc t=0: h0 = 0 (fill ALL h columns here; x staged in phase 2)
      const int fo = (tid >> 5) * AST + ((tid & 31) << 4);
      uint4 z4; z4.x = 0; z4.y = 0; z4.z = 0; z4.w = 0;
      *(uint4*)&Ahi[fo] = z4; *(uint4*)&Ahi[fo + 8] = z4;
      *(uint4*)&Alo[fo] = z4; *(uint4*)&Alo[fo + 8] = z4;
    }
    __syncthreads();

    // ---- MFMA kt 0..7 (cols 0..255) overlaps drain of cols 256..511 ----
    float4_t acc0 = {breg, breg, breg, breg};
    float4_t acc1 = {0.f, 0.f, 0.f, 0.f};
    const int abase = l15 * AST + q * 8;
    MFMA_RANGE(0, 8);

    // ---- phase 2: drain rest; stage cols 256..511 (+x); MFMA kt 8..KT ----
    if (!is_t0) {
      asm volatile("s_waitcnt vmcnt(0)" ::: "memory");
      __builtin_amdgcn_sched_barrier(0);   // fence: SPLITC stays below the wait
      SPLITC(v2, 2); SPLITC(v3, 3);
    }
    if (!IS_DEC && tid < 384) {  // x tile -> LDS
      int row = tid / 24, c4 = tid % 24;
      int off = row * AST + 512 + c4 * 4;
      half4_t hi4, lo4;
      float f0 = xv0.x, f1 = xv0.y, f2 = xv0.z, f3 = xv0.w;
      f16 a = (f16)f0, b = (f16)f1, cc = (f16)f2, d = (f16)f3;
      hi4[0] = a; hi4[1] = b; hi4[2] = cc; hi4[3] = d;
      lo4[0] = (f16)(f0 - (float)a); lo4[1] = (f16)(f1 - (float)b);
      lo4[2] = (f16)(f2 - (float)cc); lo4[3] = (f16)(f3 - (float)d);
      *(half4_t*)&Ahi[off] = hi4; *(half4_t*)&Alo[off] = lo4;
    }
    __syncthreads();
    MFMA_RANGE(8, KT);
    {
      float4_t C = acc0 + acc1;
      #pragma unroll
      for (int i = 0; i < 4; i++)
        red[(q * 4 + i) * RST + nt * 32 + dh * 16 + l15] = C[i];
    }
    __syncthreads();

    // ---- elementwise (c in VGPR, fast activations), h -> LLC ----
    {
      float ig = red[eb * RST + ed];
      float fg = red[eb * RST + 32 + ed];
      float gg = red[eb * RST + 64 + ed];
      float og = red[eb * RST + 96 + ed];
      float cn = sigmoid_fast(fg) * c_reg + sigmoid_fast(ig) * tanh_fast(gg);
      c_reg = cn;
      llc_store_f32(&hout[(size_t)(r0 + eb) * HDIM + d0 + ed],
                    sigmoid_fast(og) * tanh_fast(cn));
    }
    wait_vm0();       // own h store is in LLC
    __syncthreads();  // whole block's h stores are in LLC

    // ---- flag goes out FIRST (critical path); y-work overlaps the handoff ----
    const int done = t - t_begin + 1;
    const bool do_bar = IS_DEC || t < TT - 1;
    if (do_bar && tid == 0) llc_store_i32(&flags[rt * 16 + jt], done);

    // dec: fused y = fc(h_t) partials (k-split across waves) — AFTER flag.
    // Barrier scoped to jt<5 blocks (block-uniform); others poll earlier.
    if (IS_DEC && jt < 5) {
      float4_t ya = {0.f, 0.f, 0.f, 0.f};
      #pragma unroll
      for (int kk = 0; kk < 2; kk++) {
        const int kt = wv * 2 + kk;
        const int ao = l15 * AST + kt * 32 + q * 8;
        half8_t ahi = *(const half8_t*)&Ahi[ao];
        half8_t alo = *(const half8_t*)&Alo[ao];
        ya = __builtin_amdgcn_mfma_f32_16x16x32_f16(ahi, Fhi[kk], ya, 0, 0, 0);
        ya = __builtin_amdgcn_mfma_f32_16x16x32_f16(alo, Fhi[kk], ya, 0, 0, 0);
        ya = __builtin_amdgcn_mfma_f32_16x16x32_f16(ahi, Flo[kk], ya, 0, 0, 0);
      }
      #pragma unroll
      for (int i = 0; i < 4; i++)
        ypart[wv * 260 + (q * 4 + i) * 16 + l15] = ya[i];
      __syncthreads();  // uniform within this block (jt is block-uniform)
      if (tid < 256) {
        float acc = ybias;
        #pragma unroll
        for (int w8 = 0; w8 < 8; w8++) acc += ypart[w8 * 260 + tid];
        recon[(size_t)(r0 + (tid >> 4)) * ROWSTRIDE + (size_t)(t - 1) * DDIM +
              jt * 16 + (tid & 15)] = acc;
      }
    }

    // ---- group barrier: 4-deep pipelined lane-parallel flag poll ----
    if (do_bar) {
      if (tid < 64) poll_flag4(flags + rt * 16 + (tid & 15), done);
      __syncthreads();
    }
  }

  // ---- dec: recon col 255 = fc(h_256 = hA) ----
  if (IS_DEC) {
    if (jt >= 5) return;
    {
      const float4* base =
          (const float4*)(hA + (size_t)r0 * HDIM) + (tid >> 5) * 128 + (tid & 31);
      float4 v0, v1, v2, v3;
      llc_load_4xf4_cols(base, v0, v1, v2, v3);
      __builtin_amdgcn_sched_barrier(0);
      SPLITC(v0, 0); SPLITC(v1, 1); SPLITC(v2, 2); SPLITC(v3, 3);
    }
    __syncthreads();
    {
      float4_t ya = {0.f, 0.f, 0.f, 0.f};
      #pragma unroll
      for (int kk = 0; kk < 2; kk++) {
        const int kt = wv * 2 + kk;
        const int ao = l15 * AST + kt * 32 + q * 8;
        half8_t ahi = *(const half8_t*)&Ahi[ao];
        half8_t alo = *(const half8_t*)&Alo[ao];
        ya = __builtin_amdgcn_mfma_f32_16x16x32_f16(ahi, Fhi[kk], ya, 0, 0, 0);
        ya = __builtin_amdgcn_mfma_f32_16x16x32_f16(alo, Fhi[kk], ya, 0, 0, 0);
        ya = __builtin_amdgcn_mfma_f32_16x16x32_f16(ahi, Flo[kk], ya, 0, 0, 0);
      }
      #pragma unroll
      for (int i = 0; i < 4; i++)
        ypart[wv * 260 + (q * 4 + i) * 16 + l15] = ya[i];
    }
    __syncthreads();
    if (tid < 256) {
      float acc = ybias;
      #pragma unroll
      for (int w8 = 0; w8 < 8; w8++) acc += ypart[w8 * 260 + tid];
      recon[(size_t)(r0 + (tid >> 4)) * ROWSTRIDE + (size_t)255 * DDIM +
            jt * 16 + (tid & 15)] = acc;
    }
  }
  #undef SPLITC
  #undef MFMA_RANGE
}

// ---------------- vector quantizer ----------------------------------------------
__global__ __launch_bounds__(256) void vq_kernel(
    const float* __restrict__ z, const float* __restrict__ emb,
    float* __restrict__ quant, float* __restrict__ vq_part,
    float* __restrict__ out_idx) {
  __shared__ float sz[512];
  __shared__ float sd[256];
  __shared__ int si[256];
  int b = blockIdx.x, tid = threadIdx.x;
  sz[tid] = z[(size_t)b * HDIM + tid];
  sz[tid + 256] = z[(size_t)b * HDIM + 256 + tid];
  __syncthreads();
  float bd = 3.4e38f;
  int bk = 0;
  for (int k = tid; k < 512; k += 256) {
    const float4* e4 = (const float4*)(emb + (size_t)k * HDIM);
    const float4* z4 = (const float4*)sz;
    float dot = 0.f, ee = 0.f;
    #pragma unroll 4
    for (int qq = 0; qq < 128; qq++) {
      float4 ev = e4[qq], zv = z4[qq];
      dot += ev.x * zv.x + ev.y * zv.y + ev.z * zv.z + ev.w * zv.w;
      ee += ev.x * ev.x + ev.y * ev.y + ev.z * ev.z + ev.w * ev.w;
    }
    float dist = ee - 2.f * dot;
    if (dist < bd) { bd = dist; bk = k; }
  }
  sd[tid] = bd; si[tid] = bk;
  __syncthreads();
  for (int s = 128; s > 0; s >>= 1) {
    if (tid < s) {
      float od = sd[tid + s]; int ok = si[tid + s];
      if (od < sd[tid] || (od == sd[tid] && ok < si[tid])) { sd[tid] = od; si[tid] = ok; }
    }
    __syncthreads();
  }
  int kbest = si[0];
  __syncthreads();
  float e0 = emb[(size_t)kbest * HDIM + tid];
  float e1 = emb[(size_t)kbest * HDIM + 256 + tid];
  quant[(size_t)b * HDIM + tid] = e0;
  quant[(size_t)b * HDIM + 256 + tid] = e1;
  float q0 = e0 - sz[tid], q1 = e1 - sz[tid + 256];
  sd[tid] = q0 * q0 + q1 * q1;
  __syncthreads();
  for (int st = 128; st > 0; st >>= 1) {
    if (tid < st) sd[tid] += sd[tid + st];
    __syncthreads();
  }
  if (tid == 0) { vq_part[b] = sd[0]; out_idx[b] = (float)kbest; }
}

__global__ __launch_bounds__(256) void vq_reduce_kernel(const float* __restrict__ vq_part,
                                                        float* __restrict__ out_loss) {
  __shared__ float s[256];
  int tid = threadIdx.x;
  s[tid] = vq_part[tid];
  __syncthreads();
  for (int st = 128; st > 0; st >>= 1) {
    if (tid < st) s[tid] += s[tid + st];
    __syncthreads();
  }
  if (tid == 0) out_loss[0] = s[0] * 1.25f / (float)(BB * HDIM);
}

extern "C" void kernel_launch(void* const* d_in, const int* in_sizes, int n_in,
                              void* d_out, int out_size, void* d_ws, size_t ws_size,
                              hipStream_t stream) {
  const float* traj = (const float*)d_in[0];
  const float* eWih = (const float*)d_in[2];
  const float* eWhh = (const float*)d_in[3];
  const float* eb1  = (const float*)d_in[4];
  const float* eb2  = (const float*)d_in[5];
  const float* emb  = (const float*)d_in[6];
  const float* dWih = (const float*)d_in[7];
  const float* dWhh = (const float*)d_in[8];
  const float* db1  = (const float*)d_in[9];
  const float* db2  = (const float*)d_in[10];
  const float* fcW  = (const float*)d_in[11];
  const float* fcb  = (const float*)d_in[12];

  float* out = (float*)d_out;
  float* recon = out;
  float* out_loss = out + 5242880;
  float* out_idx = out + 5242881;

  float* ws = (float*)d_ws;
  float* hA      = ws + WS_HA;
  float* cD      = ws + WS_CD;
  int*   bar     = (int*)(ws + WS_BAR);
  float* hB      = ws + WS_HB;
  float* quant   = ws + WS_QUANT;
  float* vq_part = ws + WS_VQP;
  float* b_enc   = ws + WS_BENC;
  float* b_dec0  = ws + WS_BDEC0;
  float* b_eff   = ws + WS_BEFF;
  float* W_eff   = ws + WS_WEFF;

  // zero hA, cD, flags
  zero_kernel<<<257, 256, 0, stream>>>((float4*)ws, 65792);
  bias_init_kernel<<<8, 256, 0, stream>>>(eb1, eb2, db1, db2, dWih, fcb,
                                          b_enc, b_dec0, b_eff);
  fold_kernel<<<2048, 256, 0, stream>>>(dWih, dWhh, fcW, W_eff);

  // encoder: t=0..255 persistent; z lands in hA; flags [0..255]
  lstm_persist<0><<<256, 512, 0, stream>>>(
      eWhh, eWih, b_enc, traj, nullptr, nullptr, nullptr, nullptr, hA, hB, bar);

  vq_kernel<<<256, 256, 0, stream>>>(hA, emb, quant, vq_part, out_idx);
  vq_reduce_kernel<<<1, 256, 0, stream>>>(vq_part, out_loss);

  // decoder t=0 (plain dWhh, x=0): h_1 -> hB, c_1 -> cD
  lstm_step_kernel<<<512, 256, 0, stream>>>(dWhh, b_dec0, quant, cD, hB);
  // decoder t=1..255 persistent with W_eff; recon fused; flags [256..511]
  lstm_persist<1><<<256, 512, 0, stream>>>(
      W_eff, nullptr, b_eff, nullptr, cD, fcW, fcb, recon, hA, hB, bar + 256);
}